// Round 21
// baseline (114.003 us; speedup 1.0000x reference)
//
#include <hip/hip_runtime.h>

#define N_NODES 100000
#define N_PAD 100032
#define N_EDGES 1600000
#define HID 150
#define KPAD 160
#define HROW 168
#define OUTF 64
#define BSH 9
#define BUKN 512
#define NBUK ((N_NODES + BUKN - 1) / BUKN)   // 196 buckets
#define CAP 10240
#define TILE 4096
#define NTILE ((N_EDGES + TILE - 1) / TILE)  // 391 tiles
#define W1B_N (10 * 64 * 8)                  // 5120
#define W2T_N (128 * KPAD)                   // 20480

typedef short bf16x8 __attribute__((ext_vector_type(8)));
typedef float f32x4 __attribute__((ext_vector_type(4)));

__device__ __forceinline__ unsigned short f2bf(float f) {
    union { float f; unsigned u; } v; v.f = f;
    unsigned r = (v.u + 0x7FFFu + ((v.u >> 16) & 1u)) >> 16;
    return (unsigned short)r;
}

__device__ __forceinline__ float bf2f(unsigned short b) {
    union { unsigned u; float f; } v;
    v.u = ((unsigned)b) << 16;
    return v.f;
}

// ---------------- init0 (1 tiny block): zero bukcnt ----------------
__global__ __launch_bounds__(256) void k_init0(int* __restrict__ bukcnt) {
    int tid = threadIdx.x;
    if (tid < NBUK) bukcnt[tid] = 0;
}

// ---------------- partition: weight packing (blocks 0-99) + x4 pad + edge binning ------
__global__ __launch_bounds__(256) void k_part(const float* __restrict__ x,
                                              float4* __restrict__ x4,
                                              const int* __restrict__ src,
                                              const int* __restrict__ dst,
                                              int* __restrict__ bukcnt,
                                              unsigned int* __restrict__ pairbuf,
                                              const float* __restrict__ W1s,
                                              const float* __restrict__ W1n,
                                              const float* __restrict__ b1,
                                              const float* __restrict__ W2s,
                                              const float* __restrict__ W2n,
                                              unsigned short* __restrict__ W1B,
                                              unsigned short* __restrict__ W2T) {
    __shared__ int cnt[NBUK];
    __shared__ int gbase[NBUK];
    int tid = threadIdx.x;
    int idx = blockIdx.x * 256 + tid;

    if (idx < W1B_N) {
        int t = idx >> 9;
        int r = idx & 511;
        int ln = r >> 3;
        int j = r & 7;
        int q = ln >> 4;
        int c = t * 16 + (ln & 15);
        float v = 0.0f;
        if (q == 0 && c < HID) {
            if (j < 3)       v = W1s[j * HID + c];
            else if (j == 3) v = b1[c];
            else if (j < 7)  v = W1n[(j - 4) * HID + c];
        }
        W1B[idx] = f2bf(v);
    } else if (idx < W1B_N + W2T_N) {
        int i2 = idx - W1B_N;
        int c = i2 / KPAD, k = i2 - c * KPAD;
        float v = 0.0f;
        if (k < HID) v = (c < 64) ? W2s[k * 64 + c] : W2n[k * 64 + (c - 64)];
        W2T[i2] = f2bf(v);
    }

    if (idx < N_NODES)
        x4[idx] = make_float4(x[idx * 3 + 0], x[idx * 3 + 1], x[idx * 3 + 2], 0.0f);

    int e0 = blockIdx.x * TILE;
    int n = min(TILE, N_EDGES - e0);

    for (int i = tid; i < NBUK; i += 256) cnt[i] = 0;
    __syncthreads();

    int myb[16];
    int mypos[16];
    unsigned int myv[16];
    #pragma unroll
    for (int j = 0; j < 16; ++j) {
        int ei = tid + j * 256;
        myb[j] = -1;
        if (ei < n) {
            int s = src[e0 + ei];
            int d = dst[e0 + ei];
            int b = d >> BSH;
            myb[j] = b;
            myv[j] = ((unsigned int)(d & (BUKN - 1)) << 17) | (unsigned int)s;
            mypos[j] = atomicAdd(&cnt[b], 1);
        }
    }
    __syncthreads();

    if (tid < NBUK) {
        int c = cnt[tid];
        gbase[tid] = c ? (tid * CAP + atomicAdd(&bukcnt[tid], c)) : 0;
    }
    __syncthreads();

    #pragma unroll
    for (int j = 0; j < 16; ++j) {
        if (myb[j] >= 0)
            pairbuf[gbase[myb[j]] + mypos[j]] = myv[j];
    }
}

// ---------------- per-bucket CSR finish: hist + scan + rows/invd + scatter ----------
__global__ __launch_bounds__(512) void k_fine(const int* __restrict__ bukcnt,
                                              const unsigned int* __restrict__ pairbuf,
                                              int2* __restrict__ rows,
                                              float* __restrict__ invd,
                                              int* __restrict__ csr_src) {
    __shared__ int deg[BUKN];
    __shared__ int sc[BUKN];
    int tid = threadIdx.x;
    int b = blockIdx.x;
    int n0 = b << BSH;
    int lo = b * CAP;
    int hi = lo + bukcnt[b];

    deg[tid] = 0;
    __syncthreads();
    for (int i = lo + tid; i < hi; i += 512)
        atomicAdd(&deg[pairbuf[i] >> 17], 1);
    __syncthreads();

    int d = deg[tid];
    sc[tid] = d;
    __syncthreads();
    for (int o = 1; o < 512; o <<= 1) {
        int a = sc[tid];
        int ap = (tid >= o) ? sc[tid - o] : 0;
        __syncthreads();
        sc[tid] = a + ap;
        __syncthreads();
    }
    int r = lo + sc[tid] - d;
    int node = n0 + tid;
    if (node < N_NODES) {
        rows[node] = make_int2(r, r + d);
        invd[node] = 1.0f / fmaxf((float)d, 1.0f);
    }
    __syncthreads();
    deg[tid] = r;
    __syncthreads();
    for (int i = lo + tid; i < hi; i += 512) {
        unsigned int v = pairbuf[i];
        int dl = v >> 17;
        int ofs = atomicAdd(&deg[dl], 1);
        csr_src[ofs] = (int)(v & 0x1FFFF);
    }
}

// ---------------- fused agg1 + layer1(MFMA) + layer2(MFMA), 2 waves/tile ----------------
__global__ __launch_bounds__(256, 4) void k_gemm(
        const float4* __restrict__ x4,
        const int2* __restrict__ rows,
        const int* __restrict__ csr_src,
        const float* __restrict__ invd,
        const unsigned short* __restrict__ W1B,
        const unsigned short* __restrict__ W2T,
        const float* __restrict__ b2,
        unsigned short* __restrict__ ob) {
    __shared__ unsigned short shH[32 * HROW];   // 10752 B
    __shared__ float shXN[32][3];
    const int blk_n0 = blockIdx.x * 32;
    const int tid = threadIdx.x;
    const int lane = tid & 63;
    const int w = tid >> 6;       // 0..3
    const int tile = w >> 1;      // 0..1
    const int h = w & 1;          // half
    const int c16 = lane & 15;
    const int quad = lane >> 4;
    const int tn0 = tile * 16;

    // ---- (a) gather: 8 lanes/node, 8 nodes/wave
    {
        int j = lane >> 3;
        int sub = lane & 7;
        int nj = blk_n0 + tn0 + h * 8 + j;
        float s0 = 0.f, s1 = 0.f, s2 = 0.f;
        if (nj < N_NODES) {
            int2 re = rows[nj];
            for (int i = re.x + sub; i < re.y; i += 8) {
                float4 v = x4[csr_src[i]];
                s0 += v.x; s1 += v.y; s2 += v.z;
            }
        }
        s0 += __shfl_xor(s0, 1, 64); s0 += __shfl_xor(s0, 2, 64); s0 += __shfl_xor(s0, 4, 64);
        s1 += __shfl_xor(s1, 1, 64); s1 += __shfl_xor(s1, 2, 64); s1 += __shfl_xor(s1, 4, 64);
        s2 += __shfl_xor(s2, 1, 64); s2 += __shfl_xor(s2, 2, 64); s2 += __shfl_xor(s2, 4, 64);
        if (sub == 0) {
            float id = (nj < N_NODES) ? invd[nj] : 0.0f;
            int rloc = tn0 + h * 8 + j;
            shXN[rloc][0] = s0 * id;
            shXN[rloc][1] = s1 * id;
            shXN[rloc][2] = s2 * id;
        }
    }
    __syncthreads();

    // ---- (b) layer-1 A-fragment + 5 MFMAs per wave
    bf16x8 a8 = (bf16x8){0, 0, 0, 0, 0, 0, 0, 0};
    if (quad == 0) {
        int node = blk_n0 + tn0 + c16;
        float4 xs = make_float4(0.f, 0.f, 0.f, 0.f);
        if (node < N_NODES) xs = x4[node];
        float xn0 = shXN[tn0 + c16][0];
        float xn1 = shXN[tn0 + c16][1];
        float xn2 = shXN[tn0 + c16][2];
        union { unsigned int u[4]; bf16x8 v; } t;
        t.u[0] = (unsigned int)f2bf(xs.x) | ((unsigned int)f2bf(xs.y) << 16);
        t.u[1] = (unsigned int)f2bf(xs.z) | (0x3F80u << 16);   // bf16(1.0)
        t.u[2] = (unsigned int)f2bf(xn0) | ((unsigned int)f2bf(xn1) << 16);
        t.u[3] = (unsigned int)f2bf(xn2);
        a8 = t.v;
    }

    #pragma unroll
    for (int m = 0; m < 5; ++m) {
        int t10 = h * 5 + m;
        bf16x8 b = *(const bf16x8*)&W1B[(t10 * 64 + lane) * 8];
        f32x4 z = __builtin_amdgcn_mfma_f32_16x16x32_bf16(
                      a8, b, (f32x4){0.f, 0.f, 0.f, 0.f}, 0, 0, 0);
        #pragma unroll
        for (int i = 0; i < 4; ++i) {
            float hh = fmaxf(z[i], 0.0f);
            shH[(tn0 + quad * 4 + i) * HROW + t10 * 16 + c16] = f2bf(hh);
        }
    }
    __syncthreads();

    // ---- (c) layer-2: 4 col-tiles for this half
    const int ko = quad * 8;
    f32x4 acc[4];
    #pragma unroll
    for (int t = 0; t < 4; ++t) acc[t] = (f32x4){0.f, 0.f, 0.f, 0.f};

    #pragma unroll
    for (int ks = 0; ks < 5; ++ks) {
        int k0 = ks * 32;
        bf16x8 a = *(const bf16x8*)&shH[(tn0 + c16) * HROW + k0 + ko];
        #pragma unroll
        for (int tt = 0; tt < 4; ++tt) {
            int t = h * 4 + tt;
            bf16x8 b = *(const bf16x8*)&W2T[(t * 16 + c16) * KPAD + k0 + ko];
            acc[tt] = __builtin_amdgcn_mfma_f32_16x16x32_bf16(a, b, acc[tt], 0, 0, 0);
        }
    }

    const int rbase = blk_n0 + tn0 + quad * 4;
    #pragma unroll
    for (int tt = 0; tt < 4; ++tt) {
        int cc = (h * 4 + tt) * 16 + c16;
        float badd = (h == 0) ? b2[cc] : 0.0f;
        #pragma unroll
        for (int i = 0; i < 4; ++i) {
            int node = rbase + i;
            if (node < N_NODES) ob[(size_t)node * 128 + cc] = f2bf(acc[tt][i] + badd);
        }
    }
}

// ---------------- layer-2 pull: 8-lane group per node, 4-wide batched gathers ----------
__global__ __launch_bounds__(256) void k_pull(const int2* __restrict__ rows,
                                              const int* __restrict__ csr_src,
                                              const unsigned short* __restrict__ ob,
                                              const float* __restrict__ invd,
                                              float* __restrict__ out) {
    int wid = blockIdx.x * 4 + (threadIdx.x >> 6);
    int lane = threadIdx.x & 63;
    int g = lane >> 3;
    int t = lane & 7;
    int n = wid * 8 + g;
    if (n >= N_NODES) return;
    int2 re = rows[n];

    float acc[8];
    #pragma unroll
    for (int q = 0; q < 8; ++q) acc[q] = 0.0f;

    int i = re.x;
    // 4-wide batched main loop: forces 4 independent gathers in flight
    for (; i + 4 <= re.y; i += 4) {
        int s0 = csr_src[i + 0];
        int s1 = csr_src[i + 1];
        int s2 = csr_src[i + 2];
        int s3 = csr_src[i + 3];
        bf16x8 v0 = *(const bf16x8*)&ob[(size_t)s0 * 128 + 64 + t * 8];
        bf16x8 v1 = *(const bf16x8*)&ob[(size_t)s1 * 128 + 64 + t * 8];
        bf16x8 v2 = *(const bf16x8*)&ob[(size_t)s2 * 128 + 64 + t * 8];
        bf16x8 v3 = *(const bf16x8*)&ob[(size_t)s3 * 128 + 64 + t * 8];
        #pragma unroll
        for (int q = 0; q < 8; ++q) {
            acc[q] += bf2f((unsigned short)v0[q]);
            acc[q] += bf2f((unsigned short)v1[q]);
            acc[q] += bf2f((unsigned short)v2[q]);
            acc[q] += bf2f((unsigned short)v3[q]);
        }
    }
    for (; i < re.y; ++i) {
        int s = csr_src[i];
        bf16x8 v = *(const bf16x8*)&ob[(size_t)s * 128 + 64 + t * 8];
        #pragma unroll
        for (int q = 0; q < 8; ++q) acc[q] += bf2f((unsigned short)v[q]);
    }

    float id = invd[n];
    bf16x8 sv = *(const bf16x8*)&ob[(size_t)n * 128 + t * 8];
    f32x4 o0, o1;
    o0[0] = bf2f((unsigned short)sv[0]) + acc[0] * id;
    o0[1] = bf2f((unsigned short)sv[1]) + acc[1] * id;
    o0[2] = bf2f((unsigned short)sv[2]) + acc[2] * id;
    o0[3] = bf2f((unsigned short)sv[3]) + acc[3] * id;
    o1[0] = bf2f((unsigned short)sv[4]) + acc[4] * id;
    o1[1] = bf2f((unsigned short)sv[5]) + acc[5] * id;
    o1[2] = bf2f((unsigned short)sv[6]) + acc[6] * id;
    o1[3] = bf2f((unsigned short)sv[7]) + acc[7] * id;
    *(f32x4*)&out[(size_t)n * OUTF + t * 8]     = o0;
    *(f32x4*)&out[(size_t)n * OUTF + t * 8 + 4] = o1;
}

// ---------------- launcher ----------------

static inline size_t al256(size_t v) { return (v + 255) & ~(size_t)255; }

extern "C" void kernel_launch(void* const* d_in, const int* in_sizes, int n_in,
                              void* d_out, int out_size, void* d_ws, size_t ws_size,
                              hipStream_t stream) {
    const float* x   = (const float*)d_in[0];
    const int*   src = (const int*)d_in[1];
    const int*   dst = (const int*)d_in[2];
    const float* W1s = (const float*)d_in[3];
    const float* W1n = (const float*)d_in[4];
    const float* b1  = (const float*)d_in[5];
    const float* W2s = (const float*)d_in[6];
    const float* W2n = (const float*)d_in[7];
    const float* b2  = (const float*)d_in[8];
    float* out = (float*)d_out;

    char* ws = (char*)d_ws;
    size_t off = 0;
    int2*  rows      = (int2*)(ws + off); off += al256((size_t)N_NODES * 8);
    int*   csr_src   = (int*)(ws + off); off += al256((size_t)NBUK * CAP * 4);
    float* invd      = (float*)(ws + off); off += al256((size_t)N_NODES * 4);
    unsigned short* ob = (unsigned short*)(ws + off); off += al256((size_t)N_NODES * 128 * 2);
    float4* x4       = (float4*)(ws + off); off += al256((size_t)N_NODES * 16);
    unsigned int* pairbuf = (unsigned int*)(ws + off); off += al256((size_t)NBUK * CAP * 4);
    int*   bukcnt    = (int*)(ws + off); off += al256((size_t)NBUK * 4);
    unsigned short* W1B = (unsigned short*)(ws + off); off += al256((size_t)W1B_N * 2);
    unsigned short* W2T = (unsigned short*)(ws + off); off += al256((size_t)W2T_N * 2);

    // 1. zero bukcnt (tiny)
    k_init0<<<1, 256, 0, stream>>>(bukcnt);
    // 2. partition (+ distributed weight packing + x4 pad)
    k_part<<<NTILE, 256, 0, stream>>>(x, x4, src, dst, bukcnt, pairbuf,
                                      W1s, W1n, b1, W2s, W2n, W1B, W2T);
    // 3. per-bucket CSR finish
    k_fine<<<NBUK, 512, 0, stream>>>(bukcnt, pairbuf, rows, invd, csr_src);
    // 4. fused agg1 + layer1(MFMA) + layer2(MFMA)
    {
        int blocks = N_PAD / 32;                 // 3126
        k_gemm<<<blocks, 256, 0, stream>>>(x4, rows, csr_src, invd, W1B, W2T, b2, ob);
    }
    // 5. layer-2 pull (batched gathers)
    {
        int blocks = (N_NODES + 31) / 32;
        k_pull<<<blocks, 256, 0, stream>>>(rows, csr_src, ob, invd, out);
    }
}

// Round 22
// 112.893 us; speedup vs baseline: 1.0098x; 1.0098x over previous
//
#include <hip/hip_runtime.h>

#define N_NODES 100000
#define N_PAD 100032
#define N_EDGES 1600000
#define HID 150
#define KPAD 160
#define HROW 168
#define OUTF 64
#define BSH 9
#define BUKN 512
#define NBUK ((N_NODES + BUKN - 1) / BUKN)   // 196 buckets
#define CAP 10240
#define TILE 4096
#define NTILE ((N_EDGES + TILE - 1) / TILE)  // 391 tiles
#define W1B_N (10 * 64 * 8)                  // 5120
#define W2T_N (128 * KPAD)                   // 20480

typedef short bf16x8 __attribute__((ext_vector_type(8)));
typedef float f32x4 __attribute__((ext_vector_type(4)));

__device__ __forceinline__ unsigned short f2bf(float f) {
    union { float f; unsigned u; } v; v.f = f;
    unsigned r = (v.u + 0x7FFFu + ((v.u >> 16) & 1u)) >> 16;
    return (unsigned short)r;
}

__device__ __forceinline__ float bf2f(unsigned short b) {
    union { unsigned u; float f; } v;
    v.u = ((unsigned)b) << 16;
    return v.f;
}

// ---------------- init0 (1 tiny block): zero bukcnt ----------------
__global__ __launch_bounds__(256) void k_init0(int* __restrict__ bukcnt) {
    int tid = threadIdx.x;
    if (tid < NBUK) bukcnt[tid] = 0;
}

// ---------------- partition: weight packing (blocks 0-99) + x4 pad + edge binning ------
__global__ __launch_bounds__(256) void k_part(const float* __restrict__ x,
                                              float4* __restrict__ x4,
                                              const int* __restrict__ src,
                                              const int* __restrict__ dst,
                                              int* __restrict__ bukcnt,
                                              unsigned int* __restrict__ pairbuf,
                                              const float* __restrict__ W1s,
                                              const float* __restrict__ W1n,
                                              const float* __restrict__ b1,
                                              const float* __restrict__ W2s,
                                              const float* __restrict__ W2n,
                                              unsigned short* __restrict__ W1B,
                                              unsigned short* __restrict__ W2T) {
    __shared__ int cnt[NBUK];
    __shared__ int gbase[NBUK];
    int tid = threadIdx.x;
    int idx = blockIdx.x * 256 + tid;

    if (idx < W1B_N) {
        int t = idx >> 9;
        int r = idx & 511;
        int ln = r >> 3;
        int j = r & 7;
        int q = ln >> 4;
        int c = t * 16 + (ln & 15);
        float v = 0.0f;
        if (q == 0 && c < HID) {
            if (j < 3)       v = W1s[j * HID + c];
            else if (j == 3) v = b1[c];
            else if (j < 7)  v = W1n[(j - 4) * HID + c];
        }
        W1B[idx] = f2bf(v);
    } else if (idx < W1B_N + W2T_N) {
        int i2 = idx - W1B_N;
        int c = i2 / KPAD, k = i2 - c * KPAD;
        float v = 0.0f;
        if (k < HID) v = (c < 64) ? W2s[k * 64 + c] : W2n[k * 64 + (c - 64)];
        W2T[i2] = f2bf(v);
    }

    if (idx < N_NODES)
        x4[idx] = make_float4(x[idx * 3 + 0], x[idx * 3 + 1], x[idx * 3 + 2], 0.0f);

    int e0 = blockIdx.x * TILE;
    int n = min(TILE, N_EDGES - e0);

    for (int i = tid; i < NBUK; i += 256) cnt[i] = 0;
    __syncthreads();

    int myb[16];
    int mypos[16];
    unsigned int myv[16];
    #pragma unroll
    for (int j = 0; j < 16; ++j) {
        int ei = tid + j * 256;
        myb[j] = -1;
        if (ei < n) {
            int s = src[e0 + ei];
            int d = dst[e0 + ei];
            int b = d >> BSH;
            myb[j] = b;
            myv[j] = ((unsigned int)(d & (BUKN - 1)) << 17) | (unsigned int)s;
            mypos[j] = atomicAdd(&cnt[b], 1);
        }
    }
    __syncthreads();

    if (tid < NBUK) {
        int c = cnt[tid];
        gbase[tid] = c ? (tid * CAP + atomicAdd(&bukcnt[tid], c)) : 0;
    }
    __syncthreads();

    #pragma unroll
    for (int j = 0; j < 16; ++j) {
        if (myb[j] >= 0)
            pairbuf[gbase[myb[j]] + mypos[j]] = myv[j];
    }
}

// ---------------- per-bucket CSR finish: hist + scan + rows/invd + scatter ----------
__global__ __launch_bounds__(512) void k_fine(const int* __restrict__ bukcnt,
                                              const unsigned int* __restrict__ pairbuf,
                                              int2* __restrict__ rows,
                                              float* __restrict__ invd,
                                              int* __restrict__ csr_src) {
    __shared__ int deg[BUKN];
    __shared__ int sc[BUKN];
    int tid = threadIdx.x;
    int b = blockIdx.x;
    int n0 = b << BSH;
    int lo = b * CAP;
    int hi = lo + bukcnt[b];

    deg[tid] = 0;
    __syncthreads();
    for (int i = lo + tid; i < hi; i += 512)
        atomicAdd(&deg[pairbuf[i] >> 17], 1);
    __syncthreads();

    int d = deg[tid];
    sc[tid] = d;
    __syncthreads();
    for (int o = 1; o < 512; o <<= 1) {
        int a = sc[tid];
        int ap = (tid >= o) ? sc[tid - o] : 0;
        __syncthreads();
        sc[tid] = a + ap;
        __syncthreads();
    }
    int r = lo + sc[tid] - d;
    int node = n0 + tid;
    if (node < N_NODES) {
        rows[node] = make_int2(r, r + d);
        invd[node] = 1.0f / fmaxf((float)d, 1.0f);
    }
    __syncthreads();
    deg[tid] = r;
    __syncthreads();
    for (int i = lo + tid; i < hi; i += 512) {
        unsigned int v = pairbuf[i];
        int dl = v >> 17;
        int ofs = atomicAdd(&deg[dl], 1);
        csr_src[ofs] = (int)(v & 0x1FFFF);
    }
}

// ---------------- fused agg1 + layer1(MFMA) + layer2(MFMA), 2 waves/tile ----------------
__global__ __launch_bounds__(256, 2) void k_gemm(
        const float4* __restrict__ x4,
        const int2* __restrict__ rows,
        const int* __restrict__ csr_src,
        const float* __restrict__ invd,
        const unsigned short* __restrict__ W1B,
        const unsigned short* __restrict__ W2T,
        const float* __restrict__ b2,
        unsigned short* __restrict__ ob) {
    __shared__ unsigned short shH[32 * HROW];   // 10752 B
    __shared__ float shXN[32][3];
    const int blk_n0 = blockIdx.x * 32;
    const int tid = threadIdx.x;
    const int lane = tid & 63;
    const int w = tid >> 6;       // 0..3
    const int tile = w >> 1;      // 0..1
    const int h = w & 1;          // half
    const int c16 = lane & 15;
    const int quad = lane >> 4;
    const int tn0 = tile * 16;

    // ---- (a) gather: 8 lanes/node, 8 nodes/wave
    {
        int j = lane >> 3;
        int sub = lane & 7;
        int nj = blk_n0 + tn0 + h * 8 + j;
        float s0 = 0.f, s1 = 0.f, s2 = 0.f;
        if (nj < N_NODES) {
            int2 re = rows[nj];
            for (int i = re.x + sub; i < re.y; i += 8) {
                float4 v = x4[csr_src[i]];
                s0 += v.x; s1 += v.y; s2 += v.z;
            }
        }
        s0 += __shfl_xor(s0, 1, 64); s0 += __shfl_xor(s0, 2, 64); s0 += __shfl_xor(s0, 4, 64);
        s1 += __shfl_xor(s1, 1, 64); s1 += __shfl_xor(s1, 2, 64); s1 += __shfl_xor(s1, 4, 64);
        s2 += __shfl_xor(s2, 1, 64); s2 += __shfl_xor(s2, 2, 64); s2 += __shfl_xor(s2, 4, 64);
        if (sub == 0) {
            float id = (nj < N_NODES) ? invd[nj] : 0.0f;
            int rloc = tn0 + h * 8 + j;
            shXN[rloc][0] = s0 * id;
            shXN[rloc][1] = s1 * id;
            shXN[rloc][2] = s2 * id;
        }
    }
    __syncthreads();

    // ---- (b) layer-1 A-fragment + 5 MFMAs per wave
    bf16x8 a8 = (bf16x8){0, 0, 0, 0, 0, 0, 0, 0};
    if (quad == 0) {
        int node = blk_n0 + tn0 + c16;
        float4 xs = make_float4(0.f, 0.f, 0.f, 0.f);
        if (node < N_NODES) xs = x4[node];
        float xn0 = shXN[tn0 + c16][0];
        float xn1 = shXN[tn0 + c16][1];
        float xn2 = shXN[tn0 + c16][2];
        union { unsigned int u[4]; bf16x8 v; } t;
        t.u[0] = (unsigned int)f2bf(xs.x) | ((unsigned int)f2bf(xs.y) << 16);
        t.u[1] = (unsigned int)f2bf(xs.z) | (0x3F80u << 16);   // bf16(1.0)
        t.u[2] = (unsigned int)f2bf(xn0) | ((unsigned int)f2bf(xn1) << 16);
        t.u[3] = (unsigned int)f2bf(xn2);
        a8 = t.v;
    }

    #pragma unroll
    for (int m = 0; m < 5; ++m) {
        int t10 = h * 5 + m;
        bf16x8 b = *(const bf16x8*)&W1B[(t10 * 64 + lane) * 8];
        f32x4 z = __builtin_amdgcn_mfma_f32_16x16x32_bf16(
                      a8, b, (f32x4){0.f, 0.f, 0.f, 0.f}, 0, 0, 0);
        #pragma unroll
        for (int i = 0; i < 4; ++i) {
            float hh = fmaxf(z[i], 0.0f);
            shH[(tn0 + quad * 4 + i) * HROW + t10 * 16 + c16] = f2bf(hh);
        }
    }
    __syncthreads();

    // ---- (c) layer-2: 4 col-tiles for this half
    const int ko = quad * 8;
    f32x4 acc[4];
    #pragma unroll
    for (int t = 0; t < 4; ++t) acc[t] = (f32x4){0.f, 0.f, 0.f, 0.f};

    #pragma unroll
    for (int ks = 0; ks < 5; ++ks) {
        int k0 = ks * 32;
        bf16x8 a = *(const bf16x8*)&shH[(tn0 + c16) * HROW + k0 + ko];
        #pragma unroll
        for (int tt = 0; tt < 4; ++tt) {
            int t = h * 4 + tt;
            bf16x8 b = *(const bf16x8*)&W2T[(t * 16 + c16) * KPAD + k0 + ko];
            acc[tt] = __builtin_amdgcn_mfma_f32_16x16x32_bf16(a, b, acc[tt], 0, 0, 0);
        }
    }

    const int rbase = blk_n0 + tn0 + quad * 4;
    #pragma unroll
    for (int tt = 0; tt < 4; ++tt) {
        int cc = (h * 4 + tt) * 16 + c16;
        float badd = (h == 0) ? b2[cc] : 0.0f;
        #pragma unroll
        for (int i = 0; i < 4; ++i) {
            int node = rbase + i;
            if (node < N_NODES) ob[(size_t)node * 128 + cc] = f2bf(acc[tt][i] + badd);
        }
    }
}

// ---------------- layer-2 pull: one 8-lane group per node, pipelined edge walk ----------
__global__ __launch_bounds__(256) void k_pull(const int2* __restrict__ rows,
                                              const int* __restrict__ csr_src,
                                              const unsigned short* __restrict__ ob,
                                              const float* __restrict__ invd,
                                              float* __restrict__ out) {
    int wid = blockIdx.x * 4 + (threadIdx.x >> 6);
    int lane = threadIdx.x & 63;
    int g = lane >> 3;
    int t = lane & 7;
    int n = wid * 8 + g;
    if (n >= N_NODES) return;
    int2 re = rows[n];

    float acc[8];
    #pragma unroll
    for (int q = 0; q < 8; ++q) acc[q] = 0.0f;

    #pragma unroll 4
    for (int i = re.x; i < re.y; ++i) {
        int s = csr_src[i];
        bf16x8 v = *(const bf16x8*)&ob[(size_t)s * 128 + 64 + t * 8];
        #pragma unroll
        for (int q = 0; q < 8; ++q) acc[q] += bf2f((unsigned short)v[q]);
    }

    float id = invd[n];
    bf16x8 sv = *(const bf16x8*)&ob[(size_t)n * 128 + t * 8];
    f32x4 o0, o1;
    o0[0] = bf2f((unsigned short)sv[0]) + acc[0] * id;
    o0[1] = bf2f((unsigned short)sv[1]) + acc[1] * id;
    o0[2] = bf2f((unsigned short)sv[2]) + acc[2] * id;
    o0[3] = bf2f((unsigned short)sv[3]) + acc[3] * id;
    o1[0] = bf2f((unsigned short)sv[4]) + acc[4] * id;
    o1[1] = bf2f((unsigned short)sv[5]) + acc[5] * id;
    o1[2] = bf2f((unsigned short)sv[6]) + acc[6] * id;
    o1[3] = bf2f((unsigned short)sv[7]) + acc[7] * id;
    *(f32x4*)&out[(size_t)n * OUTF + t * 8]     = o0;
    *(f32x4*)&out[(size_t)n * OUTF + t * 8 + 4] = o1;
}

// ---------------- launcher ----------------

static inline size_t al256(size_t v) { return (v + 255) & ~(size_t)255; }

extern "C" void kernel_launch(void* const* d_in, const int* in_sizes, int n_in,
                              void* d_out, int out_size, void* d_ws, size_t ws_size,
                              hipStream_t stream) {
    const float* x   = (const float*)d_in[0];
    const int*   src = (const int*)d_in[1];
    const int*   dst = (const int*)d_in[2];
    const float* W1s = (const float*)d_in[3];
    const float* W1n = (const float*)d_in[4];
    const float* b1  = (const float*)d_in[5];
    const float* W2s = (const float*)d_in[6];
    const float* W2n = (const float*)d_in[7];
    const float* b2  = (const float*)d_in[8];
    float* out = (float*)d_out;

    char* ws = (char*)d_ws;
    size_t off = 0;
    int2*  rows      = (int2*)(ws + off); off += al256((size_t)N_NODES * 8);
    int*   csr_src   = (int*)(ws + off); off += al256((size_t)NBUK * CAP * 4);
    float* invd      = (float*)(ws + off); off += al256((size_t)N_NODES * 4);
    unsigned short* ob = (unsigned short*)(ws + off); off += al256((size_t)N_NODES * 128 * 2);
    float4* x4       = (float4*)(ws + off); off += al256((size_t)N_NODES * 16);
    unsigned int* pairbuf = (unsigned int*)(ws + off); off += al256((size_t)NBUK * CAP * 4);
    int*   bukcnt    = (int*)(ws + off); off += al256((size_t)NBUK * 4);
    unsigned short* W1B = (unsigned short*)(ws + off); off += al256((size_t)W1B_N * 2);
    unsigned short* W2T = (unsigned short*)(ws + off); off += al256((size_t)W2T_N * 2);

    // 1. zero bukcnt (tiny)
    k_init0<<<1, 256, 0, stream>>>(bukcnt);
    // 2. partition (+ distributed weight packing + x4 pad)
    k_part<<<NTILE, 256, 0, stream>>>(x, x4, src, dst, bukcnt, pairbuf,
                                      W1s, W1n, b1, W2s, W2n, W1B, W2T);
    // 3. per-bucket CSR finish
    k_fine<<<NBUK, 512, 0, stream>>>(bukcnt, pairbuf, rows, invd, csr_src);
    // 4. fused agg1 + layer1(MFMA) + layer2(MFMA)
    {
        int blocks = N_PAD / 32;                 // 3126
        k_gemm<<<blocks, 256, 0, stream>>>(x4, rows, csr_src, invd, W1B, W2T, b2, ob);
    }
    // 5. layer-2 pull
    {
        int blocks = (N_NODES + 31) / 32;
        k_pull<<<blocks, 256, 0, stream>>>(rows, csr_src, ob, invd, out);
    }
}